// Round 6
// baseline (268.310 us; speedup 1.0000x reference)
//
#include <hip/hip_runtime.h>

// ---------------------------------------------------------------------------
// HierarchicalAffinityLoss on MI355X, fp16-MFMA, round 6.
// loss = mean_r relu(maxDot_diff(r) - minDot_same(r) + 0.3), dots of
// row-normalized embeddings. Self-exclusion dropped (self-dot=1.0 never the
// min over ~2000 same-family dots near 0; verified rounds 3-5, absmax 0.0).
// Round-6: Gram symmetry -> only upper-triangle 64x64 tiles (0.504x work);
// each tile emits row-side AND col-side masked extremes; partials in
// [tile][contributor] slots (no atomics, each written once); finalize fused
// into reduce via done-counter (one fewer launch).
// ---------------------------------------------------------------------------

typedef __attribute__((ext_vector_type(8))) _Float16 half8;  // MFMA A/B frag
typedef __attribute__((ext_vector_type(4))) float floatx4;   // MFMA C/D
typedef __attribute__((ext_vector_type(4))) unsigned short ushort4v;

constexpr int D = 256;   // embedding dim
#define MARGIN 0.3f
// packed family table {0,1,2,1,3,3}, 3 bits each
#define FAM_PACKED 111240

// async 16B global -> LDS (wave-uniform LDS base + lane*16)
static __device__ __forceinline__ void ld_g2l16(const unsigned short* g,
                                                unsigned short* l) {
  __builtin_amdgcn_global_load_lds(
      (const __attribute__((address_space(1))) unsigned int*)(const void*)g,
      (__attribute__((address_space(3))) unsigned int*)(void*)l, 16, 0, 0);
}

static __device__ __forceinline__ unsigned packmm(float mn, float mx) {
  unsigned lo = __builtin_bit_cast(unsigned short, (_Float16)mn);
  unsigned hi = __builtin_bit_cast(unsigned short, (_Float16)mx);
  return lo | (hi << 16);
}

// K1: one wave per row -> Eh[row][:] = fp16(E/||E||), fam[row]; zero accums
__global__ __launch_bounds__(256) void prep_kernel(
    const float* __restrict__ E, const int* __restrict__ labels,
    unsigned short* __restrict__ Eh, int* __restrict__ fam,
    float* __restrict__ sumAcc, int* __restrict__ cntAcc,
    int* __restrict__ doneCnt, int B) {
  if (blockIdx.x == 0 && threadIdx.x == 0) {
    sumAcc[0] = 0.0f; cntAcc[0] = 0; doneCnt[0] = 0;
  }
  int row  = blockIdx.x * 4 + (threadIdx.x >> 6);
  int lane = threadIdx.x & 63;
  if (row >= B) return;
  float4 v = *(const float4*)&E[(long)row * D + lane * 4];
  float s = v.x * v.x + v.y * v.y + v.z * v.z + v.w * v.w;
#pragma unroll
  for (int o = 1; o < 64; o <<= 1) s += __shfl_xor(s, o);
  float rn = 1.0f / sqrtf(s);
  ushort4v o4;
  o4.x = __builtin_bit_cast(unsigned short, (_Float16)(v.x * rn));
  o4.y = __builtin_bit_cast(unsigned short, (_Float16)(v.y * rn));
  o4.z = __builtin_bit_cast(unsigned short, (_Float16)(v.z * rn));
  o4.w = __builtin_bit_cast(unsigned short, (_Float16)(v.w * rn));
  *(ushort4v*)&Eh[(long)row * D + lane * 4] = o4;
  if (lane == 0) {
    int lab = labels[row];
    int labc = lab < 0 ? 0 : (lab > 5 ? 5 : lab);
    fam[row] = (lab < 6) ? ((FAM_PACKED >> (3 * labc)) & 7) : -1;
  }
}

// K2: one wave per block; upper-triangle 64x64 tiles, row+col extremes.
__global__ __launch_bounds__(64, 4) void gram_kernel(
    const unsigned short* __restrict__ Eh, const int* __restrict__ fam,
    unsigned* __restrict__ partial, int nt, int nTasks) {
  __shared__ unsigned short Bs[64 * 64];   // 8 KB

  const int l = threadIdx.x;
  const int m = l & 15, q = l >> 4;

  // B-staging source offsets (elements): instr t stages LDS chunk c=t*64+l;
  // row=c>>3, kc=(c&7)^(row&7)  (XOR swizzle via source permutation)
  int srcRel[8];
#pragma unroll
  for (int t = 0; t < 8; ++t) {
    int c = t * 64 + l;
    int row = c >> 3;
    int kc = (c & 7) ^ (row & 7);
    srcRel[t] = row * D + kc * 8;
  }

  const int t0 = (int)(((long)blockIdx.x * nTasks) / gridDim.x);
  const int t1 = (int)(((long)(blockIdx.x + 1) * nTasks) / gridDim.x);

  // decode t0 -> (rt, ct) in rt-major triangle order (rt <= ct)
  int rt = 0, ct;
  {
    int tau = t0, rowlen = nt;
    while (tau >= rowlen) { tau -= rowlen; rowlen--; rt++; }
    ct = rt + tau;
  }

  for (int task = t0; task < t1; ++task) {
    const int r0 = rt * 64, c0 = ct * 64;
    const int famv  = fam[r0 + l];   // fam of row r0+l
    const int famcv = fam[c0 + l];   // fam of col c0+l
    const unsigned short* Asrc = Eh + (long)r0 * D;
    const unsigned short* Bsrc = Eh + (long)c0 * D;

    floatx4 acc[4][4];
#pragma unroll
    for (int mi = 0; mi < 4; ++mi)
#pragma unroll
      for (int nj = 0; nj < 4; ++nj) acc[mi][nj] = (floatx4)0.0f;

#pragma unroll
    for (int kb = 0; kb < D; kb += 64) {
      __syncthreads();   // 1-wave: WAR drain before overwriting Bs
#pragma unroll
      for (int t = 0; t < 8; ++t)
        ld_g2l16(Bsrc + kb + srcRel[t], &Bs[t * 512]);
      // A fragments direct from global (k-contiguous per lane)
      half8 a[2][4];
#pragma unroll
      for (int kh = 0; kh < 2; ++kh)
#pragma unroll
        for (int mi = 0; mi < 4; ++mi)
          a[kh][mi] = *(const half8*)
              &Asrc[(long)(mi * 16 + m) * D + kb + kh * 32 + q * 8];
      __syncthreads();   // 1-wave: vmcnt drain -> Bs valid
#pragma unroll
      for (int kh = 0; kh < 2; ++kh) {
        half8 b[4];
#pragma unroll
        for (int nj = 0; nj < 4; ++nj) {
          int row = nj * 16 + m;
          b[nj] = *(const half8*)
              &Bs[row * 64 + (((kh * 4 + q) ^ (row & 7)) << 3)];
        }
#pragma unroll
        for (int mi = 0; mi < 4; ++mi)
#pragma unroll
          for (int nj = 0; nj < 4; ++nj)
            acc[mi][nj] = __builtin_amdgcn_mfma_f32_16x16x32_f16(
                a[kh][mi], b[nj], acc[mi][nj], 0, 0, 0);
      }
    }

    // ---- fused epilogue: row-side and col-side masked extremes ----
    int famR[16], famC[4];
#pragma unroll
    for (int mi = 0; mi < 4; ++mi)
#pragma unroll
      for (int r = 0; r < 4; ++r)
        famR[mi * 4 + r] = __shfl(famv, mi * 16 + q * 4 + r);
#pragma unroll
    for (int nj = 0; nj < 4; ++nj) famC[nj] = __shfl(famcv, nj * 16 + m);

    float rMin[16], rMax[16], cMin[4], cMax[4];
#pragma unroll
    for (int i = 0; i < 16; ++i) { rMin[i] = 4.0f; rMax[i] = -4.0f; }
#pragma unroll
    for (int j = 0; j < 4; ++j) { cMin[j] = 4.0f; cMax[j] = -4.0f; }

#pragma unroll
    for (int mi = 0; mi < 4; ++mi)
#pragma unroll
      for (int nj = 0; nj < 4; ++nj)
#pragma unroll
        for (int r = 0; r < 4; ++r) {
          float d = acc[mi][nj][r];          // C/D: col=l&15, row=q*4+r
          bool same = (famR[mi * 4 + r] == famC[nj]);
          float ds = same ? d : 4.0f;
          float dd = same ? -4.0f : d;
          rMin[mi * 4 + r] = fminf(rMin[mi * 4 + r], ds);
          rMax[mi * 4 + r] = fmaxf(rMax[mi * 4 + r], dd);
          cMin[nj] = fminf(cMin[nj], ds);
          cMax[nj] = fmaxf(cMax[nj], dd);
        }

    // row-side: reduce across the 16 col lanes (xor over m bits)
#pragma unroll
    for (int o = 1; o < 16; o <<= 1)
#pragma unroll
      for (int i = 0; i < 16; ++i) {
        rMin[i] = fminf(rMin[i], __shfl_xor(rMin[i], o));
        rMax[i] = fmaxf(rMax[i], __shfl_xor(rMax[i], o));
      }
    if (m == 0) {
      unsigned* dst = partial + ((long)rt * nt + ct) * 64;
#pragma unroll
      for (int mi = 0; mi < 4; ++mi)
#pragma unroll
        for (int r = 0; r < 4; ++r)
          dst[mi * 16 + q * 4 + r] = packmm(rMin[mi * 4 + r], rMax[mi * 4 + r]);
    }
    // col-side: reduce across the 4 q lanes (xor 16, 32); skip diagonal
#pragma unroll
    for (int o = 16; o < 64; o <<= 1)
#pragma unroll
      for (int j = 0; j < 4; ++j) {
        cMin[j] = fminf(cMin[j], __shfl_xor(cMin[j], o));
        cMax[j] = fmaxf(cMax[j], __shfl_xor(cMax[j], o));
      }
    if (q == 0 && rt != ct) {
      unsigned* dst = partial + ((long)ct * nt + rt) * 64;
#pragma unroll
      for (int nj = 0; nj < 4; ++nj)
        dst[nj * 16 + m] = packmm(cMin[nj], cMax[nj]);
    }

    // advance along the triangle (rt-major)
    if (++ct == nt) { ++rt; ct = rt; }
  }
}

// K3: per-row combine of nt contributor slots; grid reduce; last block
// writes the final mean (done-counter pattern; no extra launch).
__global__ __launch_bounds__(256) void reduce_kernel(
    const unsigned* __restrict__ partial, float* __restrict__ sumAcc,
    int* __restrict__ cntAcc, int* __restrict__ doneCnt,
    float* __restrict__ out, int B, int nt) {
  int r = blockIdx.x * 256 + threadIdx.x;
  int t = r >> 6, rl = r & 63;
  const unsigned* base = partial + ((long)t * nt) * 64 + rl;
  float mn = 4.0f, mx = -4.0f;
  for (int k = 0; k < nt; ++k) {
    unsigned p = base[(long)k * 64];
    mn = fminf(mn, (float)__builtin_bit_cast(_Float16,
                                             (unsigned short)(p & 0xFFFF)));
    mx = fmaxf(mx, (float)__builtin_bit_cast(_Float16,
                                             (unsigned short)(p >> 16)));
  }
  float loss = 0.0f;
  int c = 0;
  if (mn < 3.0f && mx > -3.0f) {   // has same && has diff
    loss = fmaxf(mx - mn + MARGIN, 0.0f);
    c = 1;
  }
#pragma unroll
  for (int o = 1; o < 64; o <<= 1) {
    loss += __shfl_xor(loss, o);
    c    += __shfl_xor(c, o);
  }
  __shared__ float ls[4];
  __shared__ int   cs[4];
  if ((threadIdx.x & 63) == 0) {
    ls[threadIdx.x >> 6] = loss;
    cs[threadIdx.x >> 6] = c;
  }
  __syncthreads();
  if (threadIdx.x == 0) {
    atomicAdd(sumAcc, ls[0] + ls[1] + ls[2] + ls[3]);
    atomicAdd(cntAcc, cs[0] + cs[1] + cs[2] + cs[3]);
    __threadfence();
    int old = atomicAdd(doneCnt, 1);
    if (old == (int)gridDim.x - 1) {
      float S = atomicAdd(sumAcc, 0.0f);   // coherent read
      int   C = atomicAdd(cntAcc, 0);
      out[0] = S / (float)(C > 0 ? C : 1);
    }
  }
}

extern "C" void kernel_launch(void* const* d_in, const int* in_sizes, int n_in,
                              void* d_out, int out_size, void* d_ws, size_t ws_size,
                              hipStream_t stream) {
  const float* E      = (const float*)d_in[0];
  const int*   labels = (const int*)d_in[1];
  float*       out    = (float*)d_out;
  const int B  = in_sizes[1];        // 8192
  const int nt = B / 64;             // 128 row tiles
  const int nTasks = nt * (nt + 1) / 2;   // 8256 triangle tiles
  const int grid = nTasks / 4;       // 2064 blocks, 4 tasks each (exact)

  // ws: Eh[B*D] fp16 (4MB) | fam[B] | partial[nt*nt*64] uint (4MB) | accums
  unsigned short* Eh = (unsigned short*)d_ws;
  int* fam           = (int*)(Eh + (size_t)B * D);
  unsigned* partial  = (unsigned*)(fam + B);
  float* sumAcc      = (float*)(partial + (size_t)nt * nt * 64);
  int* cntAcc        = (int*)(sumAcc + 1);
  int* doneCnt       = cntAcc + 1;

  prep_kernel<<<dim3(B / 4), 256, 0, stream>>>(E, labels, Eh, fam,
                                               sumAcc, cntAcc, doneCnt, B);
  gram_kernel<<<dim3(grid), 64, 0, stream>>>(Eh, fam, partial, nt, nTasks);
  reduce_kernel<<<dim3(B / 256), 256, 0, stream>>>(partial, sumAcc, cntAcc,
                                                   doneCnt, out, B, nt);
}

// Round 7
// 183.698 us; speedup vs baseline: 1.4606x; 1.4606x over previous
//
#include <hip/hip_runtime.h>

// ---------------------------------------------------------------------------
// HierarchicalAffinityLoss on MI355X, fp16-MFMA, round 7.
// loss = mean_r relu(maxDot_diff(r) - minDot_same(r) + 0.3), dots of
// row-normalized embeddings. Self-exclusion dropped (self-dot=1.0 never the
// min over ~2000 same-family dots near 0; verified rounds 3-6, absmax 0.0).
// Round-7: round-6 triangle algorithm, but plain __launch_bounds__(64) --
// round-6's ",4" min-waves hint forced a 64-VGPR budget and ~550 MB of
// scratch spills (FETCH 250MB/WRITE 302MB). 128 VGPRs fits the whole
// working set (acc 64 + a-frags 32 + extremes) with zero spill.
// ---------------------------------------------------------------------------

typedef __attribute__((ext_vector_type(8))) _Float16 half8;  // MFMA A/B frag
typedef __attribute__((ext_vector_type(4))) float floatx4;   // MFMA C/D
typedef __attribute__((ext_vector_type(4))) unsigned short ushort4v;

constexpr int D = 256;   // embedding dim
#define MARGIN 0.3f
// packed family table {0,1,2,1,3,3}, 3 bits each
#define FAM_PACKED 111240

// async 16B global -> LDS (wave-uniform LDS base + lane*16)
static __device__ __forceinline__ void ld_g2l16(const unsigned short* g,
                                                unsigned short* l) {
  __builtin_amdgcn_global_load_lds(
      (const __attribute__((address_space(1))) unsigned int*)(const void*)g,
      (__attribute__((address_space(3))) unsigned int*)(void*)l, 16, 0, 0);
}

static __device__ __forceinline__ unsigned packmm(float mn, float mx) {
  unsigned lo = __builtin_bit_cast(unsigned short, (_Float16)mn);
  unsigned hi = __builtin_bit_cast(unsigned short, (_Float16)mx);
  return lo | (hi << 16);
}

// K1: one wave per row -> Eh[row][:] = fp16(E/||E||), fam[row]; zero accums
__global__ __launch_bounds__(256) void prep_kernel(
    const float* __restrict__ E, const int* __restrict__ labels,
    unsigned short* __restrict__ Eh, int* __restrict__ fam,
    float* __restrict__ sumAcc, int* __restrict__ cntAcc,
    int* __restrict__ doneCnt, int B) {
  if (blockIdx.x == 0 && threadIdx.x == 0) {
    sumAcc[0] = 0.0f; cntAcc[0] = 0; doneCnt[0] = 0;
  }
  int row  = blockIdx.x * 4 + (threadIdx.x >> 6);
  int lane = threadIdx.x & 63;
  if (row >= B) return;
  float4 v = *(const float4*)&E[(long)row * D + lane * 4];
  float s = v.x * v.x + v.y * v.y + v.z * v.z + v.w * v.w;
#pragma unroll
  for (int o = 1; o < 64; o <<= 1) s += __shfl_xor(s, o);
  float rn = 1.0f / sqrtf(s);
  ushort4v o4;
  o4.x = __builtin_bit_cast(unsigned short, (_Float16)(v.x * rn));
  o4.y = __builtin_bit_cast(unsigned short, (_Float16)(v.y * rn));
  o4.z = __builtin_bit_cast(unsigned short, (_Float16)(v.z * rn));
  o4.w = __builtin_bit_cast(unsigned short, (_Float16)(v.w * rn));
  *(ushort4v*)&Eh[(long)row * D + lane * 4] = o4;
  if (lane == 0) {
    int lab = labels[row];
    int labc = lab < 0 ? 0 : (lab > 5 ? 5 : lab);
    fam[row] = (lab < 6) ? ((FAM_PACKED >> (3 * labc)) & 7) : -1;
  }
}

// K2: one wave per block; upper-triangle 64x64 tiles, row+col extremes.
__global__ __launch_bounds__(64) void gram_kernel(
    const unsigned short* __restrict__ Eh, const int* __restrict__ fam,
    unsigned* __restrict__ partial, int nt, int nTasks) {
  __shared__ unsigned short Bs[64 * 64];   // 8 KB

  const int l = threadIdx.x;
  const int m = l & 15, q = l >> 4;

  // B-staging source offsets (elements): instr t stages LDS chunk c=t*64+l;
  // row=c>>3, kc=(c&7)^(row&7)  (XOR swizzle via source permutation)
  int srcRel[8];
#pragma unroll
  for (int t = 0; t < 8; ++t) {
    int c = t * 64 + l;
    int row = c >> 3;
    int kc = (c & 7) ^ (row & 7);
    srcRel[t] = row * D + kc * 8;
  }

  const int t0 = (int)(((long)blockIdx.x * nTasks) / gridDim.x);
  const int t1 = (int)(((long)(blockIdx.x + 1) * nTasks) / gridDim.x);

  // decode t0 -> (rt, ct) in rt-major triangle order (rt <= ct)
  int rt = 0, ct;
  {
    int tau = t0, rowlen = nt;
    while (tau >= rowlen) { tau -= rowlen; rowlen--; rt++; }
    ct = rt + tau;
  }

  for (int task = t0; task < t1; ++task) {
    const int r0 = rt * 64, c0 = ct * 64;
    const int famv  = fam[r0 + l];   // fam of row r0+l
    const int famcv = fam[c0 + l];   // fam of col c0+l
    const unsigned short* Asrc = Eh + (long)r0 * D;
    const unsigned short* Bsrc = Eh + (long)c0 * D;

    floatx4 acc[4][4];
#pragma unroll
    for (int mi = 0; mi < 4; ++mi)
#pragma unroll
      for (int nj = 0; nj < 4; ++nj) acc[mi][nj] = (floatx4)0.0f;

#pragma unroll
    for (int kb = 0; kb < D; kb += 64) {
      __syncthreads();   // 1-wave: WAR drain before overwriting Bs
#pragma unroll
      for (int t = 0; t < 8; ++t)
        ld_g2l16(Bsrc + kb + srcRel[t], &Bs[t * 512]);
      // A fragments direct from global (k-contiguous per lane)
      half8 a[2][4];
#pragma unroll
      for (int kh = 0; kh < 2; ++kh)
#pragma unroll
        for (int mi = 0; mi < 4; ++mi)
          a[kh][mi] = *(const half8*)
              &Asrc[(long)(mi * 16 + m) * D + kb + kh * 32 + q * 8];
      __syncthreads();   // 1-wave: vmcnt drain -> Bs valid
#pragma unroll
      for (int kh = 0; kh < 2; ++kh) {
        half8 b[4];
#pragma unroll
        for (int nj = 0; nj < 4; ++nj) {
          int row = nj * 16 + m;
          b[nj] = *(const half8*)
              &Bs[row * 64 + (((kh * 4 + q) ^ (row & 7)) << 3)];
        }
#pragma unroll
        for (int mi = 0; mi < 4; ++mi)
#pragma unroll
          for (int nj = 0; nj < 4; ++nj)
            acc[mi][nj] = __builtin_amdgcn_mfma_f32_16x16x32_f16(
                a[kh][mi], b[nj], acc[mi][nj], 0, 0, 0);
      }
    }

    // ---- fused epilogue: row-side and col-side masked extremes ----
    int famR[16], famC[4];
#pragma unroll
    for (int mi = 0; mi < 4; ++mi)
#pragma unroll
      for (int r = 0; r < 4; ++r)
        famR[mi * 4 + r] = __shfl(famv, mi * 16 + q * 4 + r);
#pragma unroll
    for (int nj = 0; nj < 4; ++nj) famC[nj] = __shfl(famcv, nj * 16 + m);

    float rMin[16], rMax[16], cMin[4], cMax[4];
#pragma unroll
    for (int i = 0; i < 16; ++i) { rMin[i] = 4.0f; rMax[i] = -4.0f; }
#pragma unroll
    for (int j = 0; j < 4; ++j) { cMin[j] = 4.0f; cMax[j] = -4.0f; }

#pragma unroll
    for (int mi = 0; mi < 4; ++mi)
#pragma unroll
      for (int nj = 0; nj < 4; ++nj)
#pragma unroll
        for (int r = 0; r < 4; ++r) {
          float d = acc[mi][nj][r];          // C/D: col=l&15, row=q*4+r
          bool same = (famR[mi * 4 + r] == famC[nj]);
          float ds = same ? d : 4.0f;
          float dd = same ? -4.0f : d;
          rMin[mi * 4 + r] = fminf(rMin[mi * 4 + r], ds);
          rMax[mi * 4 + r] = fmaxf(rMax[mi * 4 + r], dd);
          cMin[nj] = fminf(cMin[nj], ds);
          cMax[nj] = fmaxf(cMax[nj], dd);
        }

    // row-side: reduce across the 16 col lanes (xor over m bits)
#pragma unroll
    for (int o = 1; o < 16; o <<= 1)
#pragma unroll
      for (int i = 0; i < 16; ++i) {
        rMin[i] = fminf(rMin[i], __shfl_xor(rMin[i], o));
        rMax[i] = fmaxf(rMax[i], __shfl_xor(rMax[i], o));
      }
    if (m == 0) {
      unsigned* dst = partial + ((long)rt * nt + ct) * 64;
#pragma unroll
      for (int mi = 0; mi < 4; ++mi)
#pragma unroll
        for (int r = 0; r < 4; ++r)
          dst[mi * 16 + q * 4 + r] = packmm(rMin[mi * 4 + r], rMax[mi * 4 + r]);
    }
    // col-side: reduce across the 4 q lanes (xor 16, 32); skip diagonal
#pragma unroll
    for (int o = 16; o < 64; o <<= 1)
#pragma unroll
      for (int j = 0; j < 4; ++j) {
        cMin[j] = fminf(cMin[j], __shfl_xor(cMin[j], o));
        cMax[j] = fmaxf(cMax[j], __shfl_xor(cMax[j], o));
      }
    if (q == 0 && rt != ct) {
      unsigned* dst = partial + ((long)ct * nt + rt) * 64;
#pragma unroll
      for (int nj = 0; nj < 4; ++nj)
        dst[nj * 16 + m] = packmm(cMin[nj], cMax[nj]);
    }

    // advance along the triangle (rt-major)
    if (++ct == nt) { ++rt; ct = rt; }
  }
}

// K3: per-row combine of nt contributor slots; grid reduce; last block
// writes the final mean (done-counter pattern; no extra launch).
__global__ __launch_bounds__(256) void reduce_kernel(
    const unsigned* __restrict__ partial, float* __restrict__ sumAcc,
    int* __restrict__ cntAcc, int* __restrict__ doneCnt,
    float* __restrict__ out, int B, int nt) {
  int r = blockIdx.x * 256 + threadIdx.x;
  int t = r >> 6, rl = r & 63;
  const unsigned* base = partial + ((long)t * nt) * 64 + rl;
  float mn = 4.0f, mx = -4.0f;
  for (int k = 0; k < nt; ++k) {
    unsigned p = base[(long)k * 64];
    mn = fminf(mn, (float)__builtin_bit_cast(_Float16,
                                             (unsigned short)(p & 0xFFFF)));
    mx = fmaxf(mx, (float)__builtin_bit_cast(_Float16,
                                             (unsigned short)(p >> 16)));
  }
  float loss = 0.0f;
  int c = 0;
  if (mn < 3.0f && mx > -3.0f) {   // has same && has diff
    loss = fmaxf(mx - mn + MARGIN, 0.0f);
    c = 1;
  }
#pragma unroll
  for (int o = 1; o < 64; o <<= 1) {
    loss += __shfl_xor(loss, o);
    c    += __shfl_xor(c, o);
  }
  __shared__ float ls[4];
  __shared__ int   cs[4];
  if ((threadIdx.x & 63) == 0) {
    ls[threadIdx.x >> 6] = loss;
    cs[threadIdx.x >> 6] = c;
  }
  __syncthreads();
  if (threadIdx.x == 0) {
    atomicAdd(sumAcc, ls[0] + ls[1] + ls[2] + ls[3]);
    atomicAdd(cntAcc, cs[0] + cs[1] + cs[2] + cs[3]);
    __threadfence();
    int old = atomicAdd(doneCnt, 1);
    if (old == (int)gridDim.x - 1) {
      float S = atomicAdd(sumAcc, 0.0f);   // coherent read
      int   C = atomicAdd(cntAcc, 0);
      out[0] = S / (float)(C > 0 ? C : 1);
    }
  }
}

extern "C" void kernel_launch(void* const* d_in, const int* in_sizes, int n_in,
                              void* d_out, int out_size, void* d_ws, size_t ws_size,
                              hipStream_t stream) {
  const float* E      = (const float*)d_in[0];
  const int*   labels = (const int*)d_in[1];
  float*       out    = (float*)d_out;
  const int B  = in_sizes[1];        // 8192
  const int nt = B / 64;             // 128 row tiles
  const int nTasks = nt * (nt + 1) / 2;   // 8256 triangle tiles
  const int grid = nTasks / 4;       // 2064 blocks, 4 tasks each (exact)

  // ws: Eh[B*D] fp16 (4MB) | fam[B] | partial[nt*nt*64] uint (4MB) | accums
  unsigned short* Eh = (unsigned short*)d_ws;
  int* fam           = (int*)(Eh + (size_t)B * D);
  unsigned* partial  = (unsigned*)(fam + B);
  float* sumAcc      = (float*)(partial + (size_t)nt * nt * 64);
  int* cntAcc        = (int*)(sumAcc + 1);
  int* doneCnt       = cntAcc + 1;

  prep_kernel<<<dim3(B / 4), 256, 0, stream>>>(E, labels, Eh, fam,
                                               sumAcc, cntAcc, doneCnt, B);
  gram_kernel<<<dim3(grid), 64, 0, stream>>>(Eh, fam, partial, nt, nTasks);
  reduce_kernel<<<dim3(B / 256), 256, 0, stream>>>(partial, sumAcc, cntAcc,
                                                   doneCnt, out, B, nt);
}

// Round 8
// 139.036 us; speedup vs baseline: 1.9298x; 1.3212x over previous
//
#include <hip/hip_runtime.h>

// ---------------------------------------------------------------------------
// HierarchicalAffinityLoss on MI355X, fp16-MFMA, round 8.
// loss = mean_r relu(maxDot_diff(r) - minDot_same(r) + 0.3), dots of
// row-normalized embeddings. Self-exclusion dropped (self-dot=1.0 never the
// min over ~2000 same-family dots near 0; verified rounds 3-7, absmax 0.0).
// Round-8: NO LDS -- both MFMA fragments are 16B-contiguous per lane in
// row-major Eh, so load A and B frags directly global->VGPR. Removes the
// global_load_lds -> vmcnt(0) -> ds_read serial chain that made rounds 5/7
// latency-bound (93 us at constant per-wave task rate regardless of work).
// One triangle tile per wave (8256 waves). Reduce: 4 threads/row.
// ---------------------------------------------------------------------------

typedef __attribute__((ext_vector_type(8))) _Float16 half8;  // MFMA A/B frag
typedef __attribute__((ext_vector_type(4))) float floatx4;   // MFMA C/D
typedef __attribute__((ext_vector_type(4))) unsigned short ushort4v;

constexpr int D = 256;   // embedding dim
#define MARGIN 0.3f
// packed family table {0,1,2,1,3,3}, 3 bits each
#define FAM_PACKED 111240

static __device__ __forceinline__ unsigned packmm(float mn, float mx) {
  unsigned lo = __builtin_bit_cast(unsigned short, (_Float16)mn);
  unsigned hi = __builtin_bit_cast(unsigned short, (_Float16)mx);
  return lo | (hi << 16);
}

// K1: one wave per row -> Eh[row][:] = fp16(E/||E||), fam[row]; zero accums
__global__ __launch_bounds__(256) void prep_kernel(
    const float* __restrict__ E, const int* __restrict__ labels,
    unsigned short* __restrict__ Eh, int* __restrict__ fam,
    float* __restrict__ sumAcc, int* __restrict__ cntAcc,
    int* __restrict__ doneCnt, int B) {
  if (blockIdx.x == 0 && threadIdx.x == 0) {
    sumAcc[0] = 0.0f; cntAcc[0] = 0; doneCnt[0] = 0;
  }
  int row  = blockIdx.x * 4 + (threadIdx.x >> 6);
  int lane = threadIdx.x & 63;
  if (row >= B) return;
  float4 v = *(const float4*)&E[(long)row * D + lane * 4];
  float s = v.x * v.x + v.y * v.y + v.z * v.z + v.w * v.w;
#pragma unroll
  for (int o = 1; o < 64; o <<= 1) s += __shfl_xor(s, o);
  float rn = 1.0f / sqrtf(s);
  ushort4v o4;
  o4.x = __builtin_bit_cast(unsigned short, (_Float16)(v.x * rn));
  o4.y = __builtin_bit_cast(unsigned short, (_Float16)(v.y * rn));
  o4.z = __builtin_bit_cast(unsigned short, (_Float16)(v.z * rn));
  o4.w = __builtin_bit_cast(unsigned short, (_Float16)(v.w * rn));
  *(ushort4v*)&Eh[(long)row * D + lane * 4] = o4;
  if (lane == 0) {
    int lab = labels[row];
    int labc = lab < 0 ? 0 : (lab > 5 ? 5 : lab);
    fam[row] = (lab < 6) ? ((FAM_PACKED >> (3 * labc)) & 7) : -1;
  }
}

// K2: one wave = one upper-triangle 64x64 tile; frags direct from global.
__global__ __launch_bounds__(64) void gram_kernel(
    const unsigned short* __restrict__ Eh, const int* __restrict__ fam,
    unsigned* __restrict__ partial, int nt, int nTasks) {
  const int l = threadIdx.x;
  const int m = l & 15, q = l >> 4;

  // decode blockIdx.x -> (rt, ct), rt-major triangle order (rt <= ct)
  int rt = 0, ct;
  {
    int tau = blockIdx.x, rowlen = nt;
    while (tau >= rowlen) { tau -= rowlen; rowlen--; rt++; }
    ct = rt + tau;
  }

  const int r0 = rt * 64, c0 = ct * 64;
  const int famv  = fam[r0 + l];   // fam of row r0+l
  const int famcv = fam[c0 + l];   // fam of col c0+l
  // frag base: lane reads row (sub*16+m), k-chunk q*8
  const unsigned short* Abase = Eh + (long)r0 * D + (long)m * D + q * 8;
  const unsigned short* Bbase = Eh + (long)c0 * D + (long)m * D + q * 8;

  floatx4 acc[4][4];
#pragma unroll
  for (int mi = 0; mi < 4; ++mi)
#pragma unroll
    for (int nj = 0; nj < 4; ++nj) acc[mi][nj] = (floatx4)0.0f;

  // K = 256 = 8 kh-steps of 32; all loads independent, compiler pipelines.
#pragma unroll
  for (int ks = 0; ks < 8; ++ks) {
    const int ko = ks * 32;
    half8 a[4], b[4];
#pragma unroll
    for (int mi = 0; mi < 4; ++mi)
      a[mi] = *(const half8*)&Abase[(long)mi * 16 * D + ko];
#pragma unroll
    for (int nj = 0; nj < 4; ++nj)
      b[nj] = *(const half8*)&Bbase[(long)nj * 16 * D + ko];
#pragma unroll
    for (int mi = 0; mi < 4; ++mi)
#pragma unroll
      for (int nj = 0; nj < 4; ++nj)
        acc[mi][nj] = __builtin_amdgcn_mfma_f32_16x16x32_f16(
            a[mi], b[nj], acc[mi][nj], 0, 0, 0);
  }

  // ---- fused epilogue: row-side and col-side masked extremes ----
  int famR[16], famC[4];
#pragma unroll
  for (int mi = 0; mi < 4; ++mi)
#pragma unroll
    for (int r = 0; r < 4; ++r)
      famR[mi * 4 + r] = __shfl(famv, mi * 16 + q * 4 + r);
#pragma unroll
  for (int nj = 0; nj < 4; ++nj) famC[nj] = __shfl(famcv, nj * 16 + m);

  float rMin[16], rMax[16], cMin[4], cMax[4];
#pragma unroll
  for (int i = 0; i < 16; ++i) { rMin[i] = 4.0f; rMax[i] = -4.0f; }
#pragma unroll
  for (int j = 0; j < 4; ++j) { cMin[j] = 4.0f; cMax[j] = -4.0f; }

#pragma unroll
  for (int mi = 0; mi < 4; ++mi)
#pragma unroll
    for (int nj = 0; nj < 4; ++nj)
#pragma unroll
      for (int r = 0; r < 4; ++r) {
        float d = acc[mi][nj][r];          // C/D: col=l&15, row=q*4+r
        bool same = (famR[mi * 4 + r] == famC[nj]);
        float ds = same ? d : 4.0f;
        float dd = same ? -4.0f : d;
        rMin[mi * 4 + r] = fminf(rMin[mi * 4 + r], ds);
        rMax[mi * 4 + r] = fmaxf(rMax[mi * 4 + r], dd);
        cMin[nj] = fminf(cMin[nj], ds);
        cMax[nj] = fmaxf(cMax[nj], dd);
      }

  // row-side: reduce across the 16 col lanes (xor over m bits)
#pragma unroll
  for (int o = 1; o < 16; o <<= 1)
#pragma unroll
    for (int i = 0; i < 16; ++i) {
      rMin[i] = fminf(rMin[i], __shfl_xor(rMin[i], o));
      rMax[i] = fmaxf(rMax[i], __shfl_xor(rMax[i], o));
    }
  if (m == 0) {
    unsigned* dst = partial + ((long)rt * nt + ct) * 64;
#pragma unroll
    for (int mi = 0; mi < 4; ++mi)
#pragma unroll
      for (int r = 0; r < 4; ++r)
        dst[mi * 16 + q * 4 + r] = packmm(rMin[mi * 4 + r], rMax[mi * 4 + r]);
  }
  // col-side: reduce across the 4 q lanes (xor 16, 32); skip diagonal
#pragma unroll
  for (int o = 16; o < 64; o <<= 1)
#pragma unroll
    for (int j = 0; j < 4; ++j) {
      cMin[j] = fminf(cMin[j], __shfl_xor(cMin[j], o));
      cMax[j] = fmaxf(cMax[j], __shfl_xor(cMax[j], o));
    }
  if (q == 0 && rt != ct) {
    unsigned* dst = partial + ((long)ct * nt + rt) * 64;
#pragma unroll
    for (int nj = 0; nj < 4; ++nj)
      dst[nj * 16 + m] = packmm(cMin[nj], cMax[nj]);
  }
}

// K3: 4 threads per row combine nt contributor slots; grid reduce; last
// block writes the final mean (done-counter pattern).
__global__ __launch_bounds__(256) void reduce_kernel(
    const unsigned* __restrict__ partial, float* __restrict__ sumAcc,
    int* __restrict__ cntAcc, int* __restrict__ doneCnt,
    float* __restrict__ out, int B, int nt) {
  int gid = blockIdx.x * 256 + threadIdx.x;
  int row = gid >> 2;            // 4 threads per row
  int c   = gid & 3;
  int t = row >> 6, rl = row & 63;
  const unsigned* base = partial + ((long)t * nt) * 64 + rl;
  float mn = 4.0f, mx = -4.0f;
#pragma unroll 8
  for (int k = c; k < nt; k += 4) {
    unsigned p = base[(long)k * 64];
    mn = fminf(mn, (float)__builtin_bit_cast(_Float16,
                                             (unsigned short)(p & 0xFFFF)));
    mx = fmaxf(mx, (float)__builtin_bit_cast(_Float16,
                                             (unsigned short)(p >> 16)));
  }
  // combine the 4 contributors lanes
#pragma unroll
  for (int o = 1; o < 4; o <<= 1) {
    mn = fminf(mn, __shfl_xor(mn, o));
    mx = fmaxf(mx, __shfl_xor(mx, o));
  }
  float loss = 0.0f;
  int cc = 0;
  if (c == 0 && mn < 3.0f && mx > -3.0f) {   // has same && has diff
    loss = fmaxf(mx - mn + MARGIN, 0.0f);
    cc = 1;
  }
#pragma unroll
  for (int o = 1; o < 64; o <<= 1) {
    loss += __shfl_xor(loss, o);
    cc   += __shfl_xor(cc, o);
  }
  __shared__ float ls[4];
  __shared__ int   cs[4];
  if ((threadIdx.x & 63) == 0) {
    ls[threadIdx.x >> 6] = loss;
    cs[threadIdx.x >> 6] = cc;
  }
  __syncthreads();
  if (threadIdx.x == 0) {
    atomicAdd(sumAcc, ls[0] + ls[1] + ls[2] + ls[3]);
    atomicAdd(cntAcc, cs[0] + cs[1] + cs[2] + cs[3]);
    __threadfence();
    int old = atomicAdd(doneCnt, 1);
    if (old == (int)gridDim.x - 1) {
      float S = atomicAdd(sumAcc, 0.0f);   // coherent read
      int   C = atomicAdd(cntAcc, 0);
      out[0] = S / (float)(C > 0 ? C : 1);
    }
  }
}

extern "C" void kernel_launch(void* const* d_in, const int* in_sizes, int n_in,
                              void* d_out, int out_size, void* d_ws, size_t ws_size,
                              hipStream_t stream) {
  const float* E      = (const float*)d_in[0];
  const int*   labels = (const int*)d_in[1];
  float*       out    = (float*)d_out;
  const int B  = in_sizes[1];        // 8192
  const int nt = B / 64;             // 128 row tiles
  const int nTasks = nt * (nt + 1) / 2;   // 8256 triangle tiles

  // ws: Eh[B*D] fp16 (4MB) | fam[B] | partial[nt*nt*64] uint (4MB) | accums
  unsigned short* Eh = (unsigned short*)d_ws;
  int* fam           = (int*)(Eh + (size_t)B * D);
  unsigned* partial  = (unsigned*)(fam + B);
  float* sumAcc      = (float*)(partial + (size_t)nt * nt * 64);
  int* cntAcc        = (int*)(sumAcc + 1);
  int* doneCnt       = cntAcc + 1;

  prep_kernel<<<dim3(B / 4), 256, 0, stream>>>(E, labels, Eh, fam,
                                               sumAcc, cntAcc, doneCnt, B);
  gram_kernel<<<dim3(nTasks), 64, 0, stream>>>(Eh, fam, partial, nt, nTasks);
  reduce_kernel<<<dim3(B * 4 / 256), 256, 0, stream>>>(partial, sumAcc, cntAcc,
                                                       doneCnt, out, B, nt);
}